// Round 10
// baseline (3496.127 us; speedup 1.0000x reference)
//
#include <hip/hip_runtime.h>
#include <hip/hip_fp16.h>

typedef _Float16 f16;
typedef _Float16 f16x8 __attribute__((ext_vector_type(8)));
typedef float f32x4 __attribute__((ext_vector_type(4)));

__device__ __forceinline__ f16x8 relu8(f16x8 a) {
#if __has_builtin(__builtin_elementwise_max)
  return __builtin_elementwise_max(a, (f16x8)(f16)0);   // v_pk_max_f16 x4
#else
  f16x8 r;
#pragma unroll
  for (int i = 0; i < 8; i++) r[i] = a[i] > (f16)0 ? a[i] : (f16)0;
  return r;
#endif
}

__device__ __forceinline__ f16x8 bcast8(f16 s) {
  return (f16x8){s, s, s, s, s, s, s, s};
}

// ---------------------------------------------------------------------------
// prep: Wtp[frag=cg*32+kb2][lane*8+e] = f16(W2[kb2*32+q*8+e][cg*16+cL])
// (B-fragment order for mfma_f32_16x16x32_f16; 1 KB contiguous per fragment;
//  wave w's register slice = Wtp[w*16384 ..] is 32 KB contiguous)
// ---------------------------------------------------------------------------
__global__ __launch_bounds__(256) void k_prep(const float* __restrict__ W2,
                                              f16* __restrict__ Wtp) {
  const int t = blockIdx.x * 256 + threadIdx.x;
  const int frag = t >> 6, l = t & 63;
  const int cg = frag >> 5, kb2 = frag & 31;
  const int q = l >> 4, cL = l & 15;
  const int n = cg * 16 + cL, k0 = kb2 * 32 + q * 8;
  f16x8 o;
#pragma unroll
  for (int e = 0; e < 8; e++) o[e] = (f16)W2[(k0 + e) * 128 + n];
  *(f16x8*)(Wtp + frag * 512 + l * 8) = o;
}

// ---------------------------------------------------------------------------
// fused: 256 persistent blocks, 512 thr = 8 waves, 1 block/CU (VGPR-capped).
// Wave w owns n-slice [16w,16w+16): its W2 B-fragments are REGISTER-RESIDENT
// (bfr[32] = 128 VGPR, loaded once from Wtp; kk fully unrolled for static
// indexing). Block covers all 128 n -> no n-split, single Kmat output.
// Task = 1 i x 128 j x 128 n x 1024 k; 1280 tasks = exactly 5/block (no tail).
// K-loop LDS: only hat + w1b broadcast reads (2/wave/kk; ~60% LDS-pipe load).
// af regenerated in regs: relu(xj*w1b + hat), hat = f16(xi*W1a+b1) built once
// per task. Uniform rg>=rgmin skip trims below-diagonal j-frags (~17% MFMA).
// R6 lesson: WRITE_SIZE is the spill canary (bfr must stay in regs).
// ---------------------------------------------------------------------------
__global__ __launch_bounds__(512, 2) void k_fused(
    const float* __restrict__ x, const float* __restrict__ W1,
    const float* __restrict__ b1, const float* __restrict__ b2,
    const float* __restrict__ W3, const float* __restrict__ b3,
    const f16* __restrict__ Wtp, float* __restrict__ Kmat) {
  __shared__ f16 w1af[1024], b1f[1024], w1bf[1024];
  __shared__ f16 xs[512];
  __shared__ f16 hat[1024];
  __shared__ float part[8][128];

  const int tid = threadIdx.x;
  const int lane = tid & 63, wv = tid >> 6;
  const int cL = lane & 15, q = lane >> 4;

  // --- one-time staging of W1 tables + f16(x)
  if (tid < 128) {
    const int c8 = tid << 3;
    const float4 a0 = *(const float4*)(W1 + c8);
    const float4 a1 = *(const float4*)(W1 + c8 + 4);
    const float4 g0 = *(const float4*)(b1 + c8);
    const float4 g1 = *(const float4*)(b1 + c8 + 4);
    f16x8 oa, og;
    oa[0] = (f16)a0.x; oa[1] = (f16)a0.y; oa[2] = (f16)a0.z; oa[3] = (f16)a0.w;
    oa[4] = (f16)a1.x; oa[5] = (f16)a1.y; oa[6] = (f16)a1.z; oa[7] = (f16)a1.w;
    og[0] = (f16)g0.x; og[1] = (f16)g0.y; og[2] = (f16)g0.z; og[3] = (f16)g0.w;
    og[4] = (f16)g1.x; og[5] = (f16)g1.y; og[6] = (f16)g1.z; og[7] = (f16)g1.w;
    *(f16x8*)(&w1af[c8]) = oa;
    *(f16x8*)(&b1f[c8]) = og;
  } else if (tid < 256) {
    const int c8 = (tid - 128) << 3;
    const float4 a0 = *(const float4*)(W1 + 1024 + c8);
    const float4 a1 = *(const float4*)(W1 + 1024 + c8 + 4);
    f16x8 ob;
    ob[0] = (f16)a0.x; ob[1] = (f16)a0.y; ob[2] = (f16)a0.z; ob[3] = (f16)a0.w;
    ob[4] = (f16)a1.x; ob[5] = (f16)a1.y; ob[6] = (f16)a1.z; ob[7] = (f16)a1.w;
    *(f16x8*)(&w1bf[c8]) = ob;
  } else if (tid < 320) {
    const int c8 = (tid - 256) << 3;
    const float4 x0 = *(const float4*)(x + c8);
    const float4 x1 = *(const float4*)(x + c8 + 4);
    f16x8 ox;
    ox[0] = (f16)x0.x; ox[1] = (f16)x0.y; ox[2] = (f16)x0.z; ox[3] = (f16)x0.w;
    ox[4] = (f16)x1.x; ox[5] = (f16)x1.y; ox[6] = (f16)x1.z; ox[7] = (f16)x1.w;
    *(f16x8*)(&xs[c8]) = ox;
  }

  // --- register-resident B fragments: wave wv's 16-n slice, all 1024 k
  f16x8 bfr[32];
  {
    const f16* bsrc = Wtp + wv * 16384 + lane * 8;
    #pragma unroll
    for (int kb = 0; kb < 32; kb++)
      bfr[kb] = *(const f16x8*)(bsrc + (kb << 9));
  }

  const float b2v = b2[wv * 16 + cL];
  const float w3v = W3[wv * 16 + cL];
  const float b3s = b3[0];

  for (int t = (int)blockIdx.x; t < 1280; t += 256) {
    int jt, i;
    if (t < 128)      { jt = 0; i = t; }
    else if (t < 384) { jt = 1; i = t - 128; }
    else if (t < 768) { jt = 2; i = t - 384; }
    else              { jt = 3; i = t - 768; }
    const int j0 = jt << 7;
    const int rgmin = (i > j0) ? ((i - j0) >> 4) : 0;  // block-uniform

    __syncthreads();                    // prior task's hat/part reads done
    if (tid < 128) {                    // hat[k] = f16(xi*W1a[k] + b1[k])
      const int k8 = tid << 3;
      const f16x8 wa = *(const f16x8*)(&w1af[k8]);
      const f16x8 bb = *(const f16x8*)(&b1f[k8]);
      const f16x8 xv = bcast8(xs[i]);
      *(f16x8*)(&hat[k8]) = xv * wa + bb;
    }
    __syncthreads();

    f16 xjs[8];
    #pragma unroll
    for (int rg = 0; rg < 8; rg++) xjs[rg] = xs[j0 + rg * 16 + cL];

    f32x4 acc[8];
    #pragma unroll
    for (int rg = 0; rg < 8; rg++) acc[rg] = (f32x4){0.f, 0.f, 0.f, 0.f};

    #pragma unroll
    for (int kk = 0; kk < 32; kk++) {
      const int o = (kk << 5) + (q << 3);
      const f16x8 hv = *(const f16x8*)(&hat[o]);    // 16B broadcast read
      const f16x8 wb = *(const f16x8*)(&w1bf[o]);   // 16B broadcast read
      #pragma unroll
      for (int rg = 0; rg < 8; rg++) {
        if (rg >= rgmin) {
          const f16x8 af = relu8(bcast8(xjs[rg]) * wb + hv);
          acc[rg] = __builtin_amdgcn_mfma_f32_16x16x32_f16(af, bfr[kk], acc[rg], 0, 0, 0);
        }
      }
    }

    // --- epilogue: partial dot over this wave's 16 n, cross-wave sum via LDS
    #pragma unroll
    for (int rg = 0; rg < 8; rg++) {
      if (rg >= rgmin) {
        #pragma unroll
        for (int r = 0; r < 4; r++) {
          float s = fmaxf(acc[rg][r] + b2v, 0.f) * w3v;
          s += __shfl_xor(s, 1, 64);
          s += __shfl_xor(s, 2, 64);
          s += __shfl_xor(s, 4, 64);
          s += __shfl_xor(s, 8, 64);
          if (cL == 0) part[wv][rg * 16 + q * 4 + r] = s;  // C row = q*4+reg
        }
      }
    }
    __syncthreads();
    if (tid < 128) {
      const int j = j0 + tid;
      if (j >= i) {
        float s = part[0][tid] + part[1][tid] + part[2][tid] + part[3][tid]
                + part[4][tid] + part[5][tid] + part[6][tid] + part[7][tid];
        Kmat[i * 512 + j] = s + b3s;
      }
    }
  }
}

// ---------------------------------------------------------------------------
// atta: C = K^T K, fp32. Below-diagonal K entries UNWRITTEN -> masked to 0.
// Symmetry (pb<=qb + mirror), i-loop stops at pb+32.
// ---------------------------------------------------------------------------
__global__ __launch_bounds__(256) void k_atta(const float* __restrict__ K,
                                              float* __restrict__ C) {
  const int pb = blockIdx.x * 32, qb = blockIdx.y * 32;
  if (pb > qb) return;
  __shared__ float sp[32][33], sq[32][33];
  const int tid = threadIdx.x;
  const int tx = tid & 15, ty = tid >> 4;
  float c00 = 0.f, c01 = 0.f, c10 = 0.f, c11 = 0.f;
  for (int i0 = 0; i0 < pb + 32; i0 += 32) {
    #pragma unroll
    for (int r = 0; r < 4; r++) {
      const int e = tid + 256 * r, ii = e >> 5, pp = e & 31;
      const int irow = i0 + ii;
      sp[ii][pp] = (irow <= pb + pp) ? K[irow * 512 + pb + pp] : 0.f;
      sq[ii][pp] = (irow <= qb + pp) ? K[irow * 512 + qb + pp] : 0.f;
    }
    __syncthreads();
    #pragma unroll 8
    for (int ii = 0; ii < 32; ii++) {
      const float a0 = sp[ii][ty * 2], a1 = sp[ii][ty * 2 + 1];
      const float b0 = sq[ii][tx * 2], b1 = sq[ii][tx * 2 + 1];
      c00 = fmaf(a0, b0, c00); c01 = fmaf(a0, b1, c01);
      c10 = fmaf(a1, b0, c10); c11 = fmaf(a1, b1, c11);
    }
    __syncthreads();
  }
  const int p0 = pb + ty * 2, q0 = qb + tx * 2;
  C[p0 * 512 + q0] = c00;       C[p0 * 512 + q0 + 1] = c01;
  C[(p0 + 1) * 512 + q0] = c10; C[(p0 + 1) * 512 + q0 + 1] = c11;
  C[q0 * 512 + p0] = c00;       C[(q0 + 1) * 512 + p0] = c01;
  C[q0 * 512 + p0 + 1] = c10;   C[(q0 + 1) * 512 + p0 + 1] = c11;
}

extern "C" void kernel_launch(void* const* d_in, const int* in_sizes, int n_in,
                              void* d_out, int out_size, void* d_ws, size_t ws_size,
                              hipStream_t stream) {
  const float* x  = (const float*)d_in[0];
  const float* W1 = (const float*)d_in[1];
  const float* b1 = (const float*)d_in[2];
  const float* W2 = (const float*)d_in[3];
  const float* b2 = (const float*)d_in[4];
  const float* W3 = (const float*)d_in[5];
  const float* b3 = (const float*)d_in[6];
  float* out = (float*)d_out;
  char* ws = (char*)d_ws;

  f16* Wtp    = (f16*)ws;                          // 256 KB packed W2 B-fragments
  float* Kmat = (float*)(ws + (256 << 10));        // 1 MB triu(K) (j>=i written)

  k_prep<<<64, 256, 0, stream>>>(W2, Wtp);
  k_fused<<<256, 512, 0, stream>>>(x, W1, b1, b2, W3, b3, Wtp, Kmat);
  k_atta<<<dim3(16, 16), 256, 0, stream>>>(Kmat, out);
}

// Round 12
// 167.966 us; speedup vs baseline: 20.8145x; 20.8145x over previous
//
#include <hip/hip_runtime.h>
#include <hip/hip_fp16.h>

typedef _Float16 f16;
typedef _Float16 f16x8 __attribute__((ext_vector_type(8)));
typedef float f32x4 __attribute__((ext_vector_type(4)));

__device__ __forceinline__ f16x8 relu8(f16x8 a) {
#if __has_builtin(__builtin_elementwise_max)
  return __builtin_elementwise_max(a, (f16x8)(f16)0);   // v_pk_max_f16 x4
#else
  f16x8 r;
#pragma unroll
  for (int i = 0; i < 8; i++) r[i] = a[i] > (f16)0 ? a[i] : (f16)0;
  return r;
#endif
}

__device__ __forceinline__ f16x8 bcast8(f16 s) {
  return (f16x8){s, s, s, s, s, s, s, s};
}

// ---------------------------------------------------------------------------
// prep: Wtp[frag=cg*32+kb2][lane*8+e] = f16(W2[kb2*32+q*8+e][cg*16+cL])
// (B-fragment order for mfma_f32_16x16x32_f16; 1 KB contiguous per fragment;
//  n-half nh's slice = Wtp[nh*65536 ..] is 128 KB contiguous)
// ---------------------------------------------------------------------------
__global__ __launch_bounds__(256) void k_prep(const float* __restrict__ W2,
                                              f16* __restrict__ Wtp) {
  const int t = blockIdx.x * 256 + threadIdx.x;
  const int frag = t >> 6, l = t & 63;
  const int cg = frag >> 5, kb2 = frag & 31;
  const int q = l >> 4, cL = l & 15;
  const int n = cg * 16 + cL, k0 = kb2 * 32 + q * 8;
  f16x8 o;
#pragma unroll
  for (int e = 0; e < 8; e++) o[e] = (f16)W2[(k0 + e) * 128 + n];
  *(f16x8*)(Wtp + frag * 512 + l * 8) = o;
}

// ---------------------------------------------------------------------------
// fused: 256 persistent blocks, 512 thr = 8 waves, 1 block/CU.
// Task = 8 i x 128 j x 64 n (one nh) x 1024 k; wave wv owns i = i0+wv with
// rg=8 (all 128 j), cg=4 (the nh's 64 n) -> 32 MFMA per 6 ds_read_b128/kk.
// 320 tasks ordered t = u*2 + nh so a block's tasks share nh (<=1 w2f
// restage) and pair cheap(diagonal)+full. Strip counts per jt: 16/32/48/64
// (cumulative u-breaks 16/48/96/160 — R11 bug was 112, dropping the jt3
// diagonal block). Triangular: wave-uniform rg>=rgmin skip.
// W2 nh-slice LDS-resident (R10 lesson: register-resident W2 spills).
// WRITE_SIZE ~1 MB is the no-spill canary (R6/R10 lesson).
// ---------------------------------------------------------------------------
__global__ __launch_bounds__(512, 2) void k_fused(
    const float* __restrict__ x, const float* __restrict__ W1,
    const float* __restrict__ b1, const float* __restrict__ b2,
    const float* __restrict__ W3, const float* __restrict__ b3,
    const f16* __restrict__ Wtp,
    float* __restrict__ Kp0, float* __restrict__ Kp1) {
  __shared__ f16 w2f[65536];                 // 128 KB: current nh's B-fragments
  __shared__ f16 w1af[1024], b1f[1024], w1bf[1024];
  __shared__ f16 hat[8192];                  // 16 KB: ha rows for task's 8 i
  __shared__ f16 xs[512];                    // f16(x)

  const int tid = threadIdx.x;
  const int lane = tid & 63, wv = tid >> 6;
  const int cL = lane & 15, q = lane >> 4;

  // --- one-time staging: W1 tables + f16(x)
  if (tid < 128) {
    const int c8 = tid << 3;
    const float4 a0 = *(const float4*)(W1 + c8);
    const float4 a1 = *(const float4*)(W1 + c8 + 4);
    const float4 g0 = *(const float4*)(b1 + c8);
    const float4 g1 = *(const float4*)(b1 + c8 + 4);
    f16x8 oa, og;
    oa[0] = (f16)a0.x; oa[1] = (f16)a0.y; oa[2] = (f16)a0.z; oa[3] = (f16)a0.w;
    oa[4] = (f16)a1.x; oa[5] = (f16)a1.y; oa[6] = (f16)a1.z; oa[7] = (f16)a1.w;
    og[0] = (f16)g0.x; og[1] = (f16)g0.y; og[2] = (f16)g0.z; og[3] = (f16)g0.w;
    og[4] = (f16)g1.x; og[5] = (f16)g1.y; og[6] = (f16)g1.z; og[7] = (f16)g1.w;
    *(f16x8*)(&w1af[c8]) = oa;
    *(f16x8*)(&b1f[c8]) = og;
  } else if (tid < 256) {
    const int c8 = (tid - 128) << 3;
    const float4 a0 = *(const float4*)(W1 + 1024 + c8);
    const float4 a1 = *(const float4*)(W1 + 1024 + c8 + 4);
    f16x8 ob;
    ob[0] = (f16)a0.x; ob[1] = (f16)a0.y; ob[2] = (f16)a0.z; ob[3] = (f16)a0.w;
    ob[4] = (f16)a1.x; ob[5] = (f16)a1.y; ob[6] = (f16)a1.z; ob[7] = (f16)a1.w;
    *(f16x8*)(&w1bf[c8]) = ob;
  } else if (tid < 320) {
    const int c8 = (tid - 256) << 3;
    const float4 x0 = *(const float4*)(x + c8);
    const float4 x1 = *(const float4*)(x + c8 + 4);
    f16x8 ox;
    ox[0] = (f16)x0.x; ox[1] = (f16)x0.y; ox[2] = (f16)x0.z; ox[3] = (f16)x0.w;
    ox[4] = (f16)x1.x; ox[5] = (f16)x1.y; ox[6] = (f16)x1.z; ox[7] = (f16)x1.w;
    *(f16x8*)(&xs[c8]) = ox;
  }

  int cur_nh = -1;

  // 320 tasks: t = u*2 + nh; u -> (jt, strip of 8 i), breaks 16/48/96/160
  for (int t = (int)blockIdx.x; t < 320; t += 256) {
    const int nh = t & 1, u = t >> 1;
    int jt, s;
    if (u < 16)      { jt = 0; s = u; }
    else if (u < 48) { jt = 1; s = u - 16; }
    else if (u < 96) { jt = 2; s = u - 48; }
    else             { jt = 3; s = u - 96; }
    const int i0 = s << 3, j0 = jt << 7;
    float* __restrict__ Kp = nh ? Kp1 : Kp0;

    __syncthreads();                  // prior task's LDS reads done; covers one-time staging
    if (nh != cur_nh) {               // stage this nh's W2 fragments (128 KB)
      const f16* src = Wtp + nh * 65536;
      #pragma unroll
      for (int p = 0; p < 16; p++) {
        const int off = p * 4096 + tid * 8;
        *(f16x8*)(&w2f[off]) = *(const f16x8*)(src + off);
      }
      cur_nh = nh;
    }
    {  // hat[il][k] = f16(x[i0+il]*W1a[k] + b1[k]); 512 thr x 16 f16
      const int il_s = tid >> 6, kb = (tid & 63) << 4;
      const f16x8 xv = bcast8(xs[i0 + il_s]);
      const f16x8 wa0 = *(const f16x8*)(&w1af[kb]);
      const f16x8 wa1 = *(const f16x8*)(&w1af[kb + 8]);
      const f16x8 bb0 = *(const f16x8*)(&b1f[kb]);
      const f16x8 bb1 = *(const f16x8*)(&b1f[kb + 8]);
      *(f16x8*)(&hat[il_s * 1024 + kb])     = xv * wa0 + bb0;
      *(f16x8*)(&hat[il_s * 1024 + kb + 8]) = xv * wa1 + bb1;
    }
    __syncthreads();

    const int i = i0 + wv;
    const int dij = i - j0;
    const int rgmin = (dij > 0) ? (dij >> 4) : 0;   // wave-uniform skip

    f16 xjs[8];
    #pragma unroll
    for (int rg = 0; rg < 8; rg++) xjs[rg] = xs[j0 + rg * 16 + cL];

    f32x4 acc[8][4];
    #pragma unroll
    for (int rg = 0; rg < 8; rg++)
      #pragma unroll
      for (int cg = 0; cg < 4; cg++) acc[rg][cg] = (f32x4){0.f, 0.f, 0.f, 0.f};

    const f16* hrow  = hat + wv * 1024 + q * 8;
    const f16* wrow  = w1bf + q * 8;
    const f16* bbase = w2f + lane * 8;

    // prologue: kk=0 operands; 1-deep prefetch thereafter
    f16x8 hv_c = *(const f16x8*)(hrow);
    f16x8 wb_c = *(const f16x8*)(wrow);
    f16x8 bf_c[4];
    #pragma unroll
    for (int cg = 0; cg < 4; cg++)
      bf_c[cg] = *(const f16x8*)(bbase + (cg * 32) * 512);

    for (int kk = 0; kk < 32; ++kk) {
      f16x8 hv_n, wb_n, bf_n[4];
      const int kn = kk + 1;
      if (kn < 32) {
        hv_n = *(const f16x8*)(hrow + kn * 32);
        wb_n = *(const f16x8*)(wrow + kn * 32);
        #pragma unroll
        for (int cg = 0; cg < 4; cg++)
          bf_n[cg] = *(const f16x8*)(bbase + (cg * 32 + kn) * 512);
      }
      #pragma unroll
      for (int rg = 0; rg < 8; rg++) {
        if (rg >= rgmin) {
          const f16x8 af = relu8(bcast8(xjs[rg]) * wb_c + hv_c);
          #pragma unroll
          for (int cg = 0; cg < 4; cg++)
            acc[rg][cg] = __builtin_amdgcn_mfma_f32_16x16x32_f16(af, bf_c[cg], acc[rg][cg], 0, 0, 0);
        }
      }
      hv_c = hv_n; wb_c = wb_n;
      #pragma unroll
      for (int cg = 0; cg < 4; cg++) bf_c[cg] = bf_n[cg];
    }

    // --- epilogue: dot over this nh's 64 n; direct global writes (1 i/wave)
    float b2v[4], w3v[4];
    #pragma unroll
    for (int cg = 0; cg < 4; cg++) {
      b2v[cg] = b2[nh * 64 + cg * 16 + cL];
      w3v[cg] = W3[nh * 64 + cg * 16 + cL];
    }
    const float badd = (nh == 0) ? b3[0] : 0.f;   // b3 added exactly once
    #pragma unroll
    for (int rg = 0; rg < 8; rg++) {
      if (rg >= rgmin) {
        #pragma unroll
        for (int r = 0; r < 4; r++) {
          float ssum = 0.f;
          #pragma unroll
          for (int cg = 0; cg < 4; cg++)
            ssum = fmaf(fmaxf(acc[rg][cg][r] + b2v[cg], 0.f), w3v[cg], ssum);
          ssum += __shfl_xor(ssum, 1, 64);
          ssum += __shfl_xor(ssum, 2, 64);
          ssum += __shfl_xor(ssum, 4, 64);
          ssum += __shfl_xor(ssum, 8, 64);
          if (cL == 0) {
            const int j = j0 + rg * 16 + q * 4 + r;  // C row = q*4 + reg
            if (j >= i) Kp[i * 512 + j] = ssum + badd;
          }
        }
      }
    }
  }
}

// ---------------------------------------------------------------------------
// atta: C = K^T K, K = Kp0 + Kp1 (summed on load). Below-diagonal entries
// UNWRITTEN -> masked to 0. Symmetry (pb<=qb + mirror), i-loop stops at pb+32.
// ---------------------------------------------------------------------------
__global__ __launch_bounds__(256) void k_atta(const float* __restrict__ K0,
                                              const float* __restrict__ K1,
                                              float* __restrict__ C) {
  const int pb = blockIdx.x * 32, qb = blockIdx.y * 32;
  if (pb > qb) return;
  __shared__ float sp[32][33], sq[32][33];
  const int tid = threadIdx.x;
  const int tx = tid & 15, ty = tid >> 4;
  float c00 = 0.f, c01 = 0.f, c10 = 0.f, c11 = 0.f;
  for (int i0 = 0; i0 < pb + 32; i0 += 32) {
    #pragma unroll
    for (int r = 0; r < 4; r++) {
      const int e = tid + 256 * r, ii = e >> 5, pp = e & 31;
      const int irow = i0 + ii;
      const int ip = irow * 512 + pb + pp, iq = irow * 512 + qb + pp;
      sp[ii][pp] = (irow <= pb + pp) ? K0[ip] + K1[ip] : 0.f;
      sq[ii][pp] = (irow <= qb + pp) ? K0[iq] + K1[iq] : 0.f;
    }
    __syncthreads();
    #pragma unroll 8
    for (int ii = 0; ii < 32; ii++) {
      const float a0 = sp[ii][ty * 2], a1 = sp[ii][ty * 2 + 1];
      const float b0 = sq[ii][tx * 2], b1 = sq[ii][tx * 2 + 1];
      c00 = fmaf(a0, b0, c00); c01 = fmaf(a0, b1, c01);
      c10 = fmaf(a1, b0, c10); c11 = fmaf(a1, b1, c11);
    }
    __syncthreads();
  }
  const int p0 = pb + ty * 2, q0 = qb + tx * 2;
  C[p0 * 512 + q0] = c00;       C[p0 * 512 + q0 + 1] = c01;
  C[(p0 + 1) * 512 + q0] = c10; C[(p0 + 1) * 512 + q0 + 1] = c11;
  C[q0 * 512 + p0] = c00;       C[(q0 + 1) * 512 + p0] = c01;
  C[q0 * 512 + p0 + 1] = c10;   C[(q0 + 1) * 512 + p0 + 1] = c11;
}

extern "C" void kernel_launch(void* const* d_in, const int* in_sizes, int n_in,
                              void* d_out, int out_size, void* d_ws, size_t ws_size,
                              hipStream_t stream) {
  const float* x  = (const float*)d_in[0];
  const float* W1 = (const float*)d_in[1];
  const float* b1 = (const float*)d_in[2];
  const float* W2 = (const float*)d_in[3];
  const float* b2 = (const float*)d_in[4];
  const float* W3 = (const float*)d_in[5];
  const float* b3 = (const float*)d_in[6];
  float* out = (float*)d_out;
  char* ws = (char*)d_ws;

  f16* Wtp = (f16*)ws;                              // 256 KB packed W2 B-fragments
  float* Kp0 = (float*)(ws + (256 << 10));          // 1 MB partial K (n 0..63)
  float* Kp1 = (float*)(ws + (256 << 10) + (1 << 20));  // 1 MB partial K (n 64..127)

  k_prep<<<64, 256, 0, stream>>>(W2, Wtp);
  k_fused<<<256, 512, 0, stream>>>(x, W1, b1, b2, W3, b3, Wtp, Kp0, Kp1);
  k_atta<<<dim3(16, 16), 256, 0, stream>>>(Kp0, Kp1, out);
}

// Round 13
// 160.635 us; speedup vs baseline: 21.7645x; 1.0456x over previous
//
#include <hip/hip_runtime.h>
#include <hip/hip_fp16.h>

typedef _Float16 f16;
typedef _Float16 f16x8 __attribute__((ext_vector_type(8)));
typedef float f32x4 __attribute__((ext_vector_type(4)));

__device__ __forceinline__ f16x8 relu8(f16x8 a) {
#if __has_builtin(__builtin_elementwise_max)
  return __builtin_elementwise_max(a, (f16x8)(f16)0);   // v_pk_max_f16 x4
#else
  f16x8 r;
#pragma unroll
  for (int i = 0; i < 8; i++) r[i] = a[i] > (f16)0 ? a[i] : (f16)0;
  return r;
#endif
}

__device__ __forceinline__ f16x8 bcast8(f16 s) {
  return (f16x8){s, s, s, s, s, s, s, s};
}

// ---------------------------------------------------------------------------
// prep: Wtp[frag=cg*32+kb2][lane*8+e] = f16(W2[kb2*32+q*8+e][cg*16+cL])
// (B-fragment order for mfma_f32_16x16x32_f16; 1 KB contiguous per fragment;
//  n-half nh's slice = Wtp[nh*65536 ..] is 128 KB contiguous)
// ---------------------------------------------------------------------------
__global__ __launch_bounds__(256) void k_prep(const float* __restrict__ W2,
                                              f16* __restrict__ Wtp) {
  const int t = blockIdx.x * 256 + threadIdx.x;
  const int frag = t >> 6, l = t & 63;
  const int cg = frag >> 5, kb2 = frag & 31;
  const int q = l >> 4, cL = l & 15;
  const int n = cg * 16 + cL, k0 = kb2 * 32 + q * 8;
  f16x8 o;
#pragma unroll
  for (int e = 0; e < 8; e++) o[e] = (f16)W2[(k0 + e) * 128 + n];
  *(f16x8*)(Wtp + frag * 512 + l * 8) = o;
}

// ---------------------------------------------------------------------------
// fused: 256 persistent blocks, 512 thr = 8 waves, 1 block/CU.
// Task = 8 i x 128 j x 64 n (one nh) x 1024 k; wave wv owns i = i0+wv with
// rg=8 (all 128 j), cg=4 (the nh's 64 n) -> 32 MFMA per 6 ds_read_b128/kk.
// NO software prefetch (R12 lesson: 128-AGPR acc + prefetch regs > 256
// unified budget -> 9 MB scratch spill; direct LDS reads + 2-wave TLP
// instead). 320 tasks t = u*2 + nh: block's tasks share nh, pair
// cheap(diagonal)+full; u-breaks 16/48/96/160. Wave-uniform rg>=rgmin skip.
// W2 nh-slice LDS-resident (R10: register-resident W2 spills).
// WRITE_SIZE ~1 MB is the no-spill canary.
// ---------------------------------------------------------------------------
__global__ __launch_bounds__(512, 2) void k_fused(
    const float* __restrict__ x, const float* __restrict__ W1,
    const float* __restrict__ b1, const float* __restrict__ b2,
    const float* __restrict__ W3, const float* __restrict__ b3,
    const f16* __restrict__ Wtp,
    float* __restrict__ Kp0, float* __restrict__ Kp1) {
  __shared__ f16 w2f[65536];                 // 128 KB: current nh's B-fragments
  __shared__ f16 w1af[1024], b1f[1024], w1bf[1024];
  __shared__ f16 hat[8192];                  // 16 KB: ha rows for task's 8 i
  __shared__ f16 xs[512];                    // f16(x)

  const int tid = threadIdx.x;
  const int lane = tid & 63, wv = tid >> 6;
  const int cL = lane & 15, q = lane >> 4;

  // --- one-time staging: W1 tables + f16(x)
  if (tid < 128) {
    const int c8 = tid << 3;
    const float4 a0 = *(const float4*)(W1 + c8);
    const float4 a1 = *(const float4*)(W1 + c8 + 4);
    const float4 g0 = *(const float4*)(b1 + c8);
    const float4 g1 = *(const float4*)(b1 + c8 + 4);
    f16x8 oa, og;
    oa[0] = (f16)a0.x; oa[1] = (f16)a0.y; oa[2] = (f16)a0.z; oa[3] = (f16)a0.w;
    oa[4] = (f16)a1.x; oa[5] = (f16)a1.y; oa[6] = (f16)a1.z; oa[7] = (f16)a1.w;
    og[0] = (f16)g0.x; og[1] = (f16)g0.y; og[2] = (f16)g0.z; og[3] = (f16)g0.w;
    og[4] = (f16)g1.x; og[5] = (f16)g1.y; og[6] = (f16)g1.z; og[7] = (f16)g1.w;
    *(f16x8*)(&w1af[c8]) = oa;
    *(f16x8*)(&b1f[c8]) = og;
  } else if (tid < 256) {
    const int c8 = (tid - 128) << 3;
    const float4 a0 = *(const float4*)(W1 + 1024 + c8);
    const float4 a1 = *(const float4*)(W1 + 1024 + c8 + 4);
    f16x8 ob;
    ob[0] = (f16)a0.x; ob[1] = (f16)a0.y; ob[2] = (f16)a0.z; ob[3] = (f16)a0.w;
    ob[4] = (f16)a1.x; ob[5] = (f16)a1.y; ob[6] = (f16)a1.z; ob[7] = (f16)a1.w;
    *(f16x8*)(&w1bf[c8]) = ob;
  } else if (tid < 320) {
    const int c8 = (tid - 256) << 3;
    const float4 x0 = *(const float4*)(x + c8);
    const float4 x1 = *(const float4*)(x + c8 + 4);
    f16x8 ox;
    ox[0] = (f16)x0.x; ox[1] = (f16)x0.y; ox[2] = (f16)x0.z; ox[3] = (f16)x0.w;
    ox[4] = (f16)x1.x; ox[5] = (f16)x1.y; ox[6] = (f16)x1.z; ox[7] = (f16)x1.w;
    *(f16x8*)(&xs[c8]) = ox;
  }

  int cur_nh = -1;

  // 320 tasks: t = u*2 + nh; u -> (jt, strip of 8 i), breaks 16/48/96/160
  for (int t = (int)blockIdx.x; t < 320; t += 256) {
    const int nh = t & 1, u = t >> 1;
    int jt, s;
    if (u < 16)      { jt = 0; s = u; }
    else if (u < 48) { jt = 1; s = u - 16; }
    else if (u < 96) { jt = 2; s = u - 48; }
    else             { jt = 3; s = u - 96; }
    const int i0 = s << 3, j0 = jt << 7;
    float* __restrict__ Kp = nh ? Kp1 : Kp0;

    __syncthreads();                  // prior task's LDS reads done; covers one-time staging
    if (nh != cur_nh) {               // stage this nh's W2 fragments (128 KB)
      const f16* src = Wtp + nh * 65536;
      #pragma unroll
      for (int p = 0; p < 16; p++) {
        const int off = p * 4096 + tid * 8;
        *(f16x8*)(&w2f[off]) = *(const f16x8*)(src + off);
      }
      cur_nh = nh;
    }
    {  // hat[il][k] = f16(x[i0+il]*W1a[k] + b1[k]); 512 thr x 16 f16
      const int il_s = tid >> 6, kb = (tid & 63) << 4;
      const f16x8 xv = bcast8(xs[i0 + il_s]);
      const f16x8 wa0 = *(const f16x8*)(&w1af[kb]);
      const f16x8 wa1 = *(const f16x8*)(&w1af[kb + 8]);
      const f16x8 bb0 = *(const f16x8*)(&b1f[kb]);
      const f16x8 bb1 = *(const f16x8*)(&b1f[kb + 8]);
      *(f16x8*)(&hat[il_s * 1024 + kb])     = xv * wa0 + bb0;
      *(f16x8*)(&hat[il_s * 1024 + kb + 8]) = xv * wa1 + bb1;
    }
    __syncthreads();

    const int i = i0 + wv;
    const int dij = i - j0;
    const int rgmin = (dij > 0) ? (dij >> 4) : 0;   // wave-uniform skip

    f16 xjs[8];
    #pragma unroll
    for (int rg = 0; rg < 8; rg++) xjs[rg] = xs[j0 + rg * 16 + cL];

    f32x4 acc[8][4];
    #pragma unroll
    for (int rg = 0; rg < 8; rg++)
      #pragma unroll
      for (int cg = 0; cg < 4; cg++) acc[rg][cg] = (f32x4){0.f, 0.f, 0.f, 0.f};

    const f16* hrow  = hat + wv * 1024 + q * 8;
    const f16* wrow  = w1bf + q * 8;
    const f16* bbase = w2f + lane * 8;

    for (int kk = 0; kk < 32; ++kk) {
      const f16x8 hv = *(const f16x8*)(hrow + kk * 32);
      const f16x8 wb = *(const f16x8*)(wrow + kk * 32);
      f16x8 bf[4];
      #pragma unroll
      for (int cg = 0; cg < 4; cg++)
        bf[cg] = *(const f16x8*)(bbase + (cg * 32 + kk) * 512);
      #pragma unroll
      for (int rg = 0; rg < 8; rg++) {
        if (rg >= rgmin) {
          const f16x8 af = relu8(bcast8(xjs[rg]) * wb + hv);
          #pragma unroll
          for (int cg = 0; cg < 4; cg++)
            acc[rg][cg] = __builtin_amdgcn_mfma_f32_16x16x32_f16(af, bf[cg], acc[rg][cg], 0, 0, 0);
        }
      }
    }

    // --- epilogue: dot over this nh's 64 n; direct global writes (1 i/wave)
    float b2v[4], w3v[4];
    #pragma unroll
    for (int cg = 0; cg < 4; cg++) {
      b2v[cg] = b2[nh * 64 + cg * 16 + cL];
      w3v[cg] = W3[nh * 64 + cg * 16 + cL];
    }
    const float badd = (nh == 0) ? b3[0] : 0.f;   // b3 added exactly once
    #pragma unroll
    for (int rg = 0; rg < 8; rg++) {
      if (rg >= rgmin) {
        #pragma unroll
        for (int r = 0; r < 4; r++) {
          float ssum = 0.f;
          #pragma unroll
          for (int cg = 0; cg < 4; cg++)
            ssum = fmaf(fmaxf(acc[rg][cg][r] + b2v[cg], 0.f), w3v[cg], ssum);
          ssum += __shfl_xor(ssum, 1, 64);
          ssum += __shfl_xor(ssum, 2, 64);
          ssum += __shfl_xor(ssum, 4, 64);
          ssum += __shfl_xor(ssum, 8, 64);
          if (cL == 0) {
            const int j = j0 + rg * 16 + q * 4 + r;  // C row = q*4 + reg
            if (j >= i) Kp[i * 512 + j] = ssum + badd;
          }
        }
      }
    }
  }
}

// ---------------------------------------------------------------------------
// atta: C = K^T K, K = Kp0 + Kp1 (summed on load). Below-diagonal entries
// UNWRITTEN -> masked to 0. Symmetry (pb<=qb + mirror), i-loop stops at pb+32.
// ---------------------------------------------------------------------------
__global__ __launch_bounds__(256) void k_atta(const float* __restrict__ K0,
                                              const float* __restrict__ K1,
                                              float* __restrict__ C) {
  const int pb = blockIdx.x * 32, qb = blockIdx.y * 32;
  if (pb > qb) return;
  __shared__ float sp[32][33], sq[32][33];
  const int tid = threadIdx.x;
  const int tx = tid & 15, ty = tid >> 4;
  float c00 = 0.f, c01 = 0.f, c10 = 0.f, c11 = 0.f;
  for (int i0 = 0; i0 < pb + 32; i0 += 32) {
    #pragma unroll
    for (int r = 0; r < 4; r++) {
      const int e = tid + 256 * r, ii = e >> 5, pp = e & 31;
      const int irow = i0 + ii;
      const int ip = irow * 512 + pb + pp, iq = irow * 512 + qb + pp;
      sp[ii][pp] = (irow <= pb + pp) ? K0[ip] + K1[ip] : 0.f;
      sq[ii][pp] = (irow <= qb + pp) ? K0[iq] + K1[iq] : 0.f;
    }
    __syncthreads();
    #pragma unroll 8
    for (int ii = 0; ii < 32; ii++) {
      const float a0 = sp[ii][ty * 2], a1 = sp[ii][ty * 2 + 1];
      const float b0 = sq[ii][tx * 2], b1 = sq[ii][tx * 2 + 1];
      c00 = fmaf(a0, b0, c00); c01 = fmaf(a0, b1, c01);
      c10 = fmaf(a1, b0, c10); c11 = fmaf(a1, b1, c11);
    }
    __syncthreads();
  }
  const int p0 = pb + ty * 2, q0 = qb + tx * 2;
  C[p0 * 512 + q0] = c00;       C[p0 * 512 + q0 + 1] = c01;
  C[(p0 + 1) * 512 + q0] = c10; C[(p0 + 1) * 512 + q0 + 1] = c11;
  C[q0 * 512 + p0] = c00;       C[(q0 + 1) * 512 + p0] = c01;
  C[q0 * 512 + p0 + 1] = c10;   C[(q0 + 1) * 512 + p0 + 1] = c11;
}

extern "C" void kernel_launch(void* const* d_in, const int* in_sizes, int n_in,
                              void* d_out, int out_size, void* d_ws, size_t ws_size,
                              hipStream_t stream) {
  const float* x  = (const float*)d_in[0];
  const float* W1 = (const float*)d_in[1];
  const float* b1 = (const float*)d_in[2];
  const float* W2 = (const float*)d_in[3];
  const float* b2 = (const float*)d_in[4];
  const float* W3 = (const float*)d_in[5];
  const float* b3 = (const float*)d_in[6];
  float* out = (float*)d_out;
  char* ws = (char*)d_ws;

  f16* Wtp = (f16*)ws;                              // 256 KB packed W2 B-fragments
  float* Kp0 = (float*)(ws + (256 << 10));          // 1 MB partial K (n 0..63)
  float* Kp1 = (float*)(ws + (256 << 10) + (1 << 20));  // 1 MB partial K (n 64..127)

  k_prep<<<64, 256, 0, stream>>>(W2, Wtp);
  k_fused<<<256, 512, 0, stream>>>(x, W1, b1, b2, W3, b3, Wtp, Kp0, Kp1);
  k_atta<<<dim3(16, 16), 256, 0, stream>>>(Kp0, Kp1, out);
}

// Round 14
// 144.439 us; speedup vs baseline: 24.2048x; 1.1121x over previous
//
#include <hip/hip_runtime.h>
#include <hip/hip_fp16.h>

typedef _Float16 f16;
typedef _Float16 f16x8 __attribute__((ext_vector_type(8)));
typedef float f32x4 __attribute__((ext_vector_type(4)));

__device__ __forceinline__ f16x8 relu8(f16x8 a) {
#if __has_builtin(__builtin_elementwise_max)
  return __builtin_elementwise_max(a, (f16x8)(f16)0);   // v_pk_max_f16 x4
#else
  f16x8 r;
#pragma unroll
  for (int i = 0; i < 8; i++) r[i] = a[i] > (f16)0 ? a[i] : (f16)0;
  return r;
#endif
}

__device__ __forceinline__ f16x8 bcast8(f16 s) {
  return (f16x8){s, s, s, s, s, s, s, s};
}

// ---------------------------------------------------------------------------
// prep: Wtp[frag=cg*32+kb2][lane*8+e] = f16(W2[kb2*32+q*8+e][cg*16+cL])
// (B-fragment order for mfma_f32_16x16x32_f16; 1 KB contiguous per fragment;
//  n-half nh's slice = Wtp[nh*65536 ..] is 128 KB contiguous)
// ---------------------------------------------------------------------------
__global__ __launch_bounds__(256) void k_prep(const float* __restrict__ W2,
                                              f16* __restrict__ Wtp) {
  const int t = blockIdx.x * 256 + threadIdx.x;
  const int frag = t >> 6, l = t & 63;
  const int cg = frag >> 5, kb2 = frag & 31;
  const int q = l >> 4, cL = l & 15;
  const int n = cg * 16 + cL, k0 = kb2 * 32 + q * 8;
  f16x8 o;
#pragma unroll
  for (int e = 0; e < 8; e++) o[e] = (f16)W2[(k0 + e) * 128 + n];
  *(f16x8*)(Wtp + frag * 512 + l * 8) = o;
}

// ---------------------------------------------------------------------------
// fused: 256 persistent blocks, 512 thr = 8 waves, 1 block/CU.
// Task = 8 i x 128 j x 64 n (one nh) x 1024 k; wave wv owns i = i0+wv with
// rg=8 (all 128 j), cg=4 (the nh's 64 n) -> 32 MFMA per 6 ds_read_b128/kk.
// No software prefetch (R12: 128-AGPR acc + prefetch regs -> spill).
// TASK BALANCE (R13 lesson: naive pairing put 2 FULL tasks on some blocks ->
// 2.0 full-equiv critical path): 128 cheap diagonal tasks occupy slots
// {0..63, 256..319} so dual-task blocks b<64 get two diagonal tasks with
// complementary depth (jt+2, l2=15-l1 -> pair cost ~1.06 full-equiv, same nh);
// 192 full tasks occupy slots {64..255}, one per block. Max load 1.06.
// WRITE_SIZE ~1 MB is the no-spill canary.
// ---------------------------------------------------------------------------
__global__ __launch_bounds__(512, 2) void k_fused(
    const float* __restrict__ x, const float* __restrict__ W1,
    const float* __restrict__ b1, const float* __restrict__ b2,
    const float* __restrict__ W3, const float* __restrict__ b3,
    const f16* __restrict__ Wtp,
    float* __restrict__ Kp0, float* __restrict__ Kp1) {
  __shared__ f16 w2f[65536];                 // 128 KB: current nh's B-fragments
  __shared__ f16 w1af[1024], b1f[1024], w1bf[1024];
  __shared__ f16 hat[8192];                  // 16 KB: ha rows for task's 8 i
  __shared__ f16 xs[512];                    // f16(x)

  const int tid = threadIdx.x;
  const int lane = tid & 63, wv = tid >> 6;
  const int cL = lane & 15, q = lane >> 4;

  // --- one-time staging: W1 tables + f16(x)
  if (tid < 128) {
    const int c8 = tid << 3;
    const float4 a0 = *(const float4*)(W1 + c8);
    const float4 a1 = *(const float4*)(W1 + c8 + 4);
    const float4 g0 = *(const float4*)(b1 + c8);
    const float4 g1 = *(const float4*)(b1 + c8 + 4);
    f16x8 oa, og;
    oa[0] = (f16)a0.x; oa[1] = (f16)a0.y; oa[2] = (f16)a0.z; oa[3] = (f16)a0.w;
    oa[4] = (f16)a1.x; oa[5] = (f16)a1.y; oa[6] = (f16)a1.z; oa[7] = (f16)a1.w;
    og[0] = (f16)g0.x; og[1] = (f16)g0.y; og[2] = (f16)g0.z; og[3] = (f16)g0.w;
    og[4] = (f16)g1.x; og[5] = (f16)g1.y; og[6] = (f16)g1.z; og[7] = (f16)g1.w;
    *(f16x8*)(&w1af[c8]) = oa;
    *(f16x8*)(&b1f[c8]) = og;
  } else if (tid < 256) {
    const int c8 = (tid - 128) << 3;
    const float4 a0 = *(const float4*)(W1 + 1024 + c8);
    const float4 a1 = *(const float4*)(W1 + 1024 + c8 + 4);
    f16x8 ob;
    ob[0] = (f16)a0.x; ob[1] = (f16)a0.y; ob[2] = (f16)a0.z; ob[3] = (f16)a0.w;
    ob[4] = (f16)a1.x; ob[5] = (f16)a1.y; ob[6] = (f16)a1.z; ob[7] = (f16)a1.w;
    *(f16x8*)(&w1bf[c8]) = ob;
  } else if (tid < 320) {
    const int c8 = (tid - 256) << 3;
    const float4 x0 = *(const float4*)(x + c8);
    const float4 x1 = *(const float4*)(x + c8 + 4);
    f16x8 ox;
    ox[0] = (f16)x0.x; ox[1] = (f16)x0.y; ox[2] = (f16)x0.z; ox[3] = (f16)x0.w;
    ox[4] = (f16)x1.x; ox[5] = (f16)x1.y; ox[6] = (f16)x1.z; ox[7] = (f16)x1.w;
    *(f16x8*)(&xs[c8]) = ox;
  }

  int cur_nh = -1;

  for (int t = (int)blockIdx.x; t < 320; t += 256) {
    // --- task map (R14): cheap diagonal in {0..63, 256..319}, full in {64..255}
    int nh, jt, s;
    if (t < 64 || t >= 256) {
      const int b = (t < 64) ? t : (t - 256);
      nh = b & 1;
      const int jd = b >> 1;              // 0..31
      const int jt1 = jd >> 4, l = jd & 15;
      if (t < 64) { jt = jt1;            s = jt * 16 + l; }
      else        { jt = (jt1 + 2) & 3;  s = jt * 16 + (15 - l); }
    } else {
      const int f = t - 64;               // 0..191
      nh = f & 1;
      const int jf = f >> 1;              // 0..95
      if (jf < 16)      { jt = 1; s = jf; }
      else if (jf < 48) { jt = 2; s = jf - 16; }
      else              { jt = 3; s = jf - 48; }
    }
    const int i0 = s << 3, j0 = jt << 7;
    float* __restrict__ Kp = nh ? Kp1 : Kp0;

    __syncthreads();                  // prior task's LDS reads done; covers one-time staging
    if (nh != cur_nh) {               // stage this nh's W2 fragments (128 KB)
      const f16* src = Wtp + nh * 65536;
      #pragma unroll
      for (int p = 0; p < 16; p++) {
        const int off = p * 4096 + tid * 8;
        *(f16x8*)(&w2f[off]) = *(const f16x8*)(src + off);
      }
      cur_nh = nh;
    }
    {  // hat[il][k] = f16(x[i0+il]*W1a[k] + b1[k]); 512 thr x 16 f16
      const int il_s = tid >> 6, kb = (tid & 63) << 4;
      const f16x8 xv = bcast8(xs[i0 + il_s]);
      const f16x8 wa0 = *(const f16x8*)(&w1af[kb]);
      const f16x8 wa1 = *(const f16x8*)(&w1af[kb + 8]);
      const f16x8 bb0 = *(const f16x8*)(&b1f[kb]);
      const f16x8 bb1 = *(const f16x8*)(&b1f[kb + 8]);
      *(f16x8*)(&hat[il_s * 1024 + kb])     = xv * wa0 + bb0;
      *(f16x8*)(&hat[il_s * 1024 + kb + 8]) = xv * wa1 + bb1;
    }
    __syncthreads();

    const int i = i0 + wv;
    const int dij = i - j0;
    const int rgmin = (dij > 0) ? (dij >> 4) : 0;   // wave-uniform skip

    f16 xjs[8];
    #pragma unroll
    for (int rg = 0; rg < 8; rg++) xjs[rg] = xs[j0 + rg * 16 + cL];

    f32x4 acc[8][4];
    #pragma unroll
    for (int rg = 0; rg < 8; rg++)
      #pragma unroll
      for (int cg = 0; cg < 4; cg++) acc[rg][cg] = (f32x4){0.f, 0.f, 0.f, 0.f};

    const f16* hrow  = hat + wv * 1024 + q * 8;
    const f16* wrow  = w1bf + q * 8;
    const f16* bbase = w2f + lane * 8;

    for (int kk = 0; kk < 32; ++kk) {
      const f16x8 hv = *(const f16x8*)(hrow + kk * 32);
      const f16x8 wb = *(const f16x8*)(wrow + kk * 32);
      f16x8 bf[4];
      #pragma unroll
      for (int cg = 0; cg < 4; cg++)
        bf[cg] = *(const f16x8*)(bbase + (cg * 32 + kk) * 512);
      #pragma unroll
      for (int rg = 0; rg < 8; rg++) {
        if (rg >= rgmin) {
          const f16x8 af = relu8(bcast8(xjs[rg]) * wb + hv);
          #pragma unroll
          for (int cg = 0; cg < 4; cg++)
            acc[rg][cg] = __builtin_amdgcn_mfma_f32_16x16x32_f16(af, bf[cg], acc[rg][cg], 0, 0, 0);
        }
      }
    }

    // --- epilogue: dot over this nh's 64 n; direct global writes (1 i/wave)
    float b2v[4], w3v[4];
    #pragma unroll
    for (int cg = 0; cg < 4; cg++) {
      b2v[cg] = b2[nh * 64 + cg * 16 + cL];
      w3v[cg] = W3[nh * 64 + cg * 16 + cL];
    }
    const float badd = (nh == 0) ? b3[0] : 0.f;   // b3 added exactly once
    #pragma unroll
    for (int rg = 0; rg < 8; rg++) {
      if (rg >= rgmin) {
        #pragma unroll
        for (int r = 0; r < 4; r++) {
          float ssum = 0.f;
          #pragma unroll
          for (int cg = 0; cg < 4; cg++)
            ssum = fmaf(fmaxf(acc[rg][cg][r] + b2v[cg], 0.f), w3v[cg], ssum);
          ssum += __shfl_xor(ssum, 1, 64);
          ssum += __shfl_xor(ssum, 2, 64);
          ssum += __shfl_xor(ssum, 4, 64);
          ssum += __shfl_xor(ssum, 8, 64);
          if (cL == 0) {
            const int j = j0 + rg * 16 + q * 4 + r;  // C row = q*4 + reg
            if (j >= i) Kp[i * 512 + j] = ssum + badd;
          }
        }
      }
    }
  }
}

// ---------------------------------------------------------------------------
// atta: C = K^T K, K = Kp0 + Kp1 (summed on load). Below-diagonal entries
// UNWRITTEN -> masked to 0. Symmetry (pb<=qb + mirror), i-loop stops at pb+32.
// ---------------------------------------------------------------------------
__global__ __launch_bounds__(256) void k_atta(const float* __restrict__ K0,
                                              const float* __restrict__ K1,
                                              float* __restrict__ C) {
  const int pb = blockIdx.x * 32, qb = blockIdx.y * 32;
  if (pb > qb) return;
  __shared__ float sp[32][33], sq[32][33];
  const int tid = threadIdx.x;
  const int tx = tid & 15, ty = tid >> 4;
  float c00 = 0.f, c01 = 0.f, c10 = 0.f, c11 = 0.f;
  for (int i0 = 0; i0 < pb + 32; i0 += 32) {
    #pragma unroll
    for (int r = 0; r < 4; r++) {
      const int e = tid + 256 * r, ii = e >> 5, pp = e & 31;
      const int irow = i0 + ii;
      const int ip = irow * 512 + pb + pp, iq = irow * 512 + qb + pp;
      sp[ii][pp] = (irow <= pb + pp) ? K0[ip] + K1[ip] : 0.f;
      sq[ii][pp] = (irow <= qb + pp) ? K0[iq] + K1[iq] : 0.f;
    }
    __syncthreads();
    #pragma unroll 8
    for (int ii = 0; ii < 32; ii++) {
      const float a0 = sp[ii][ty * 2], a1 = sp[ii][ty * 2 + 1];
      const float b0 = sq[ii][tx * 2], b1 = sq[ii][tx * 2 + 1];
      c00 = fmaf(a0, b0, c00); c01 = fmaf(a0, b1, c01);
      c10 = fmaf(a1, b0, c10); c11 = fmaf(a1, b1, c11);
    }
    __syncthreads();
  }
  const int p0 = pb + ty * 2, q0 = qb + tx * 2;
  C[p0 * 512 + q0] = c00;       C[p0 * 512 + q0 + 1] = c01;
  C[(p0 + 1) * 512 + q0] = c10; C[(p0 + 1) * 512 + q0 + 1] = c11;
  C[q0 * 512 + p0] = c00;       C[(q0 + 1) * 512 + p0] = c01;
  C[q0 * 512 + p0 + 1] = c10;   C[(q0 + 1) * 512 + p0 + 1] = c11;
}

extern "C" void kernel_launch(void* const* d_in, const int* in_sizes, int n_in,
                              void* d_out, int out_size, void* d_ws, size_t ws_size,
                              hipStream_t stream) {
  const float* x  = (const float*)d_in[0];
  const float* W1 = (const float*)d_in[1];
  const float* b1 = (const float*)d_in[2];
  const float* W2 = (const float*)d_in[3];
  const float* b2 = (const float*)d_in[4];
  const float* W3 = (const float*)d_in[5];
  const float* b3 = (const float*)d_in[6];
  float* out = (float*)d_out;
  char* ws = (char*)d_ws;

  f16* Wtp = (f16*)ws;                              // 256 KB packed W2 B-fragments
  float* Kp0 = (float*)(ws + (256 << 10));          // 1 MB partial K (n 0..63)
  float* Kp1 = (float*)(ws + (256 << 10) + (1 << 20));  // 1 MB partial K (n 64..127)

  k_prep<<<64, 256, 0, stream>>>(W2, Wtp);
  k_fused<<<256, 512, 0, stream>>>(x, W1, b1, b2, W3, b3, Wtp, Kp0, Kp1);
  k_atta<<<dim3(16, 16), 256, 0, stream>>>(Kp0, Kp1, out);
}